// Round 8
// baseline (56696.124 us; speedup 1.0000x reference)
//
#include <hip/hip_runtime.h>
#include <math.h>

#define S_LEN 4096
#define L_CH  12
#define CE    64
#define CHD   128
#define WE    256
#define HD    512
#define TAGS  64
#define GW    (4*HD)      // 2048
#define XDIM  (CHD+WE)    // 384

// ws layout (float offsets)
#define WS_GX    0
#define WS_CREP  (WS_GX   + (size_t)S_LEN*GW)        // 8,388,608 floats
#define WS_HEXT  (WS_CREP + (size_t)S_LEN*CHD)       // +524,288
// hext: (S_LEN+1) rows x HD. Row r = h_{r-1} + 2.0 (row 0 = hx0+2).
// Rows 1..S_LEN double as `outs` (+2 bias) for k_out. Write-once rows ->
// zero/nonzero band check is sound, no epochs needed.

typedef float v4f __attribute__((ext_vector_type(4)));
typedef _Float16 h2v __attribute__((ext_vector_type(2)));

static __device__ __forceinline__ float sigf(float x) {
    return 1.0f / (1.0f + __expf(-x));
}
static __device__ __forceinline__ float tanhfast(float x) {
    return 1.0f - 2.0f / (__expf(2.0f * x) + 1.0f);
}
static __device__ __forceinline__ unsigned int packh2(float a, float b) {
    union { h2v h; unsigned int u; } x;
    x.h.x = (_Float16)a; x.h.y = (_Float16)b;
    return x.u;
}
static __device__ __forceinline__ h2v u2h(unsigned int u) {
    union { unsigned int u; h2v h; } x; x.u = u; return x.h;
}

// ---------------------------------------------------------------------------
// K_init: hext row 0 = hx0 + 2, rows 1..S_LEN = 0, stores bypassing caches
// (sc0 sc1) so readiness state lives at the device coherence point.
// ---------------------------------------------------------------------------
__global__ __launch_bounds__(256) void k_init(const float* __restrict__ hx0,
                                              float* __restrict__ hext) {
    size_t i = ((size_t)blockIdx.x * 256 + threadIdx.x) * 4;
    if (i >= (size_t)(S_LEN + 1) * HD) return;
    v4f v;
    if (i < HD) {
        v.x = hx0[i+0] + 2.0f; v.y = hx0[i+1] + 2.0f;
        v.z = hx0[i+2] + 2.0f; v.w = hx0[i+3] + 2.0f;
    } else {
        v.x = 0.f; v.y = 0.f; v.z = 0.f; v.w = 0.f;
    }
    float* p = hext + i;
    asm volatile("global_store_dwordx4 %0, %1, off sc0 sc1"
                 :: "v"(p), "v"(v) : "memory");
}

// ---------------------------------------------------------------------------
// K1: char LSTM. 256 blocks x 256 threads; block owns 16 words, runs 12 steps.
// ---------------------------------------------------------------------------
__global__ __launch_bounds__(256) void k_char_lstm(
    const int* __restrict__ c_seq, const float* __restrict__ char_emb,
    const float* __restrict__ c_hx0, const float* __restrict__ c_cx0,
    const float* __restrict__ Wih1, const float* __restrict__ Whh1,
    const float* __restrict__ bih1, const float* __restrict__ bhh1,
    float* __restrict__ char_rep)
{
    __shared__ float xs[16][CE + 4];
    __shared__ float hs[16][CHD + 4];
    __shared__ float cs[16][CHD + 4];
    __shared__ float gs[16][4*CHD + 4];
    const int tid = threadIdx.x;
    const int w0  = blockIdx.x * 16;

    for (int u = tid; u < 16*CHD; u += 256) {
        int w = u >> 7, k = u & (CHD-1);
        hs[w][k] = c_hx0[k];
        cs[w][k] = c_cx0[k];
    }
    __syncthreads();

    const int wg = tid & 3;
    const int rg = tid >> 2;
    const int uw = tid >> 4;
    const int uj = (tid & 15) * 8;

    for (int t = 0; t < L_CH; ++t) {
        {
            int w = tid >> 4, k4 = (tid & 15) * 4;
            int ci = c_seq[(w0 + w) * L_CH + t];
            float4 v = *(const float4*)(char_emb + (size_t)ci * CE + k4);
            *(float4*)&xs[w][k4] = v;
        }
        __syncthreads();

        float acc[8][4];
        #pragma unroll
        for (int i = 0; i < 8; ++i)
            #pragma unroll
            for (int j = 0; j < 4; ++j) acc[i][j] = 0.0f;

        for (int kc = 0; kc < CE/4; ++kc) {
            int k = kc * 4;
            float4 xv[4];
            #pragma unroll
            for (int j = 0; j < 4; ++j) xv[j] = *(const float4*)&xs[wg*4 + j][k];
            #pragma unroll
            for (int i = 0; i < 8; ++i) {
                int r = rg*8 + i;
                float4 wv = *(const float4*)(Wih1 + (size_t)r*CE + k);
                #pragma unroll
                for (int j = 0; j < 4; ++j)
                    acc[i][j] += wv.x*xv[j].x + wv.y*xv[j].y + wv.z*xv[j].z + wv.w*xv[j].w;
            }
        }
        for (int kc = 0; kc < CHD/4; ++kc) {
            int k = kc * 4;
            float4 hv[4];
            #pragma unroll
            for (int j = 0; j < 4; ++j) hv[j] = *(const float4*)&hs[wg*4 + j][k];
            #pragma unroll
            for (int i = 0; i < 8; ++i) {
                int r = rg*8 + i;
                float4 wv = *(const float4*)(Whh1 + (size_t)r*CHD + k);
                #pragma unroll
                for (int j = 0; j < 4; ++j)
                    acc[i][j] += wv.x*hv[j].x + wv.y*hv[j].y + wv.z*hv[j].z + wv.w*hv[j].w;
            }
        }
        #pragma unroll
        for (int i = 0; i < 8; ++i) {
            int r = rg*8 + i;
            float b = bih1[r] + bhh1[r];
            #pragma unroll
            for (int j = 0; j < 4; ++j) gs[wg*4 + j][r] = acc[i][j] + b;
        }
        __syncthreads();

        #pragma unroll
        for (int i = 0; i < 8; ++i) {
            int j = uj + i;
            float gi = gs[uw][j];
            float gf = gs[uw][CHD + j];
            float gg = gs[uw][2*CHD + j];
            float go = gs[uw][3*CHD + j];
            float c = sigf(gf)*cs[uw][j] + sigf(gi)*tanhfast(gg);
            cs[uw][j] = c;
            hs[uw][j] = sigf(go)*tanhfast(c);
        }
        __syncthreads();
    }
    #pragma unroll
    for (int i4 = 0; i4 < 2; ++i4) {
        float4 v;
        v.x = hs[uw][uj + i4*4 + 0]; v.y = hs[uw][uj + i4*4 + 1];
        v.z = hs[uw][uj + i4*4 + 2]; v.w = hs[uw][uj + i4*4 + 3];
        *(float4*)(char_rep + (size_t)(w0 + uw)*CHD + uj + i4*4) = v;
    }
}

// ---------------------------------------------------------------------------
// K2: Gx[t][2048] = concat(char_rep, wv)[t] @ Wih2^T + (bih2+bhh2)
// ---------------------------------------------------------------------------
__global__ __launch_bounds__(256) void k_gx(
    const int* __restrict__ w_seq, const float* __restrict__ word_emb,
    const float* __restrict__ char_rep,
    const float* __restrict__ Wih2, const float* __restrict__ bih2,
    const float* __restrict__ bhh2, float* __restrict__ Gx)
{
    __shared__ float xs[16][XDIM + 4];
    const int tid = threadIdx.x;
    const int w0  = blockIdx.x * 16;
    const int slice = blockIdx.y;

    {
        int w = tid >> 4, seg = tid & 15;
        int wsq = w_seq[w0 + w];
        #pragma unroll
        for (int i4 = 0; i4 < 6; ++i4) {
            int k = seg*24 + i4*4;
            float4 v;
            if (k < CHD) v = *(const float4*)(char_rep + (size_t)(w0+w)*CHD + k);
            else         v = *(const float4*)(word_emb + (size_t)wsq*WE + (k - CHD));
            *(float4*)&xs[w][k] = v;
        }
    }
    __syncthreads();

    const int wg = tid & 3, rg = tid >> 2;
    float acc[8][4];
    #pragma unroll
    for (int i = 0; i < 8; ++i)
        #pragma unroll
        for (int j = 0; j < 4; ++j) acc[i][j] = 0.0f;

    for (int kc = 0; kc < XDIM/4; ++kc) {
        int k = kc * 4;
        float4 xv[4];
        #pragma unroll
        for (int j = 0; j < 4; ++j) xv[j] = *(const float4*)&xs[wg*4 + j][k];
        #pragma unroll
        for (int i = 0; i < 8; ++i) {
            int r = slice*512 + rg*8 + i;
            float4 wv = *(const float4*)(Wih2 + (size_t)r*XDIM + k);
            #pragma unroll
            for (int j = 0; j < 4; ++j)
                acc[i][j] += wv.x*xv[j].x + wv.y*xv[j].y + wv.z*xv[j].z + wv.w*xv[j].w;
        }
    }
    #pragma unroll
    for (int i = 0; i < 8; ++i) {
        int r = slice*512 + rg*8 + i;
        float b = bih2[r] + bhh2[r];
        #pragma unroll
        for (int j = 0; j < 4; ++j)
            Gx[(size_t)(w0 + wg*4 + j)*GW + r] = acc[i][j] + b;
    }
}

// ---------------------------------------------------------------------------
// K3: sequential word LSTM — TWO-BLOCK fp16-dot2 design.
// 2 blocks x 1024 threads (16 waves). Block p owns outputs [p*256, p*256+256)
// = 1024 gate rows; 1 row per lane (lane: q=lane>>4 gate, iout=lane&15,
// wave w -> output jo = p*256 + w*16 + iout; row = q*512 + jo).
// Weights held IN REGISTERS as fp16 pairs: 512 halves = 256 VGPR/lane,
// ordered own-k-half first. Dots via v_dot2_f32_f16 (fp32 accumulate).
//
// Per step t (consumes h_t, produces h_{t+1}):
//  A: all waves: own-half dots from LDS h2 (ready at entry). Wave 15
//     concurrently polls the REMOTE 1KB half of hext row t (one dwordx4 per
//     lane, self-contained register-safe probes), subtracts the +2 bias
//     (deterministic), packs fp16 -> LDS.
//  B: __syncthreads (remote h2 ready)
//  C: all waves: remote-half dots
//  D: + Gx (1 float/lane, prefetched), gate gather via 4x __shfl (no LDS
//     race), nonlinearity -> h_{t+1}; lanes q==0 write h2(next parity) + hpub
//  E: __syncthreads (hpub complete)
//  F: wave 14 publishes the ENTIRE own 1KB half of row t+1 as ONE 64-lane
//     dwordx4 store (sc0 sc1) — single instruction, zero producer skew.
// c is tracked redundantly in 4 replica lanes (identical fp ops ->
// deterministic). hext rows are write-once -> band check min>0.5 sound.
// ---------------------------------------------------------------------------
__global__ __launch_bounds__(1024, 1) void k_word_lstm(
    const float* __restrict__ Gx, const float* __restrict__ Whh2,
    const float* __restrict__ cx0, float* __restrict__ hext)
{
    __shared__ __align__(16) unsigned int h2lds[2][256]; // full h row, fp16 pairs, dbuf
    __shared__ __align__(16) float hpub[256];            // own half, h+2 fp32
    const int tid  = threadIdx.x;
    const int p    = blockIdx.x;           // 0 or 1
    const int w    = tid >> 6;             // wave 0..15
    const int lane = tid & 63;
    const int q    = lane >> 4;            // gate 0..3 (i,f,g,o)
    const int iout = lane & 15;
    const int jo   = p*256 + w*16 + iout;  // output index
    const int row  = q*512 + jo;           // Whh2 / Gx gate-row
    const int own0 = p*256, rem0 = (1-p)*256;

    // ---- weights: fp32 -> fp16 pairs in registers, own-half first ----
    h2v wv[256];
    {
        const float* wr = Whh2 + (size_t)row * HD;
        #pragma unroll
        for (int c = 0; c < 64; ++c) {     // own half: 256 floats
            float4 a = *(const float4*)(wr + own0 + c*4);
            h2v t0; t0.x = (_Float16)a.x; t0.y = (_Float16)a.y;
            h2v t1; t1.x = (_Float16)a.z; t1.y = (_Float16)a.w;
            wv[c*2+0] = t0; wv[c*2+1] = t1;
        }
        #pragma unroll
        for (int c = 0; c < 64; ++c) {     // remote half
            float4 a = *(const float4*)(wr + rem0 + c*4);
            h2v t0; t0.x = (_Float16)a.x; t0.y = (_Float16)a.y;
            h2v t1; t1.x = (_Float16)a.z; t1.y = (_Float16)a.w;
            wv[128 + c*2+0] = t0; wv[128 + c*2+1] = t1;
        }
    }

    float creg = cx0[jo];                  // 4 replica lanes track identical c
    float gx_cur = Gx[row];                // t = 0

    // prologue: own half of h_0 from hext row 0 (k_init wrote hx0+2) -> LDS fp16
    if (w == 13) {
        const float* src = hext + own0 + lane*4;
        v4f pr;
        asm volatile("global_load_dwordx4 %0, %1, off sc0 sc1\n\t"
                     "s_waitcnt vmcnt(0)"
                     : "=&v"(pr) : "v"(src) : "memory");
        h2lds[0][p*128 + lane*2+0] = packh2(pr.x - 2.0f, pr.y - 2.0f);
        h2lds[0][p*128 + lane*2+1] = packh2(pr.z - 2.0f, pr.w - 2.0f);
    }
    __syncthreads();

    for (int t = 0; t < S_LEN; ++t) {
        const int par  = t & 1;
        const int parn = (t + 1) & 1;
        // prefetch next Gx value (clamped)
        int tn = (t + 1 < S_LEN) ? t + 1 : t;
        float gx_nxt = Gx[(size_t)tn*GW + row];

        // --- A: wave 15 polls remote half of row t; others go straight to dots
        if (w == 15) {
            const float* psrc = hext + (size_t)t*HD + rem0 + lane*4;
            v4f pr;
            for (;;) {
                asm volatile("global_load_dwordx4 %0, %1, off sc0 sc1\n\t"
                             "s_waitcnt vmcnt(0)"
                             : "=&v"(pr) : "v"(psrc) : "memory");
                float mn = fminf(fminf(pr.x, pr.y), fminf(pr.z, pr.w));
                if (__all(mn > 0.5f)) break;
            }
            h2lds[par][(1-p)*128 + lane*2+0] = packh2(pr.x - 2.0f, pr.y - 2.0f);
            h2lds[par][(1-p)*128 + lane*2+1] = packh2(pr.z - 2.0f, pr.w - 2.0f);
        }
        // own-half dots (wave 15 does its share after the poll)
        float acc = 0.0f;
        {
            const unsigned int* hown = &h2lds[par][p*128];
            #pragma unroll
            for (int c = 0; c < 32; ++c) {
                uint4 hh = *(const uint4*)(hown + c*4);
                acc = __builtin_amdgcn_fdot2(wv[c*4+0], u2h(hh.x), acc, false);
                acc = __builtin_amdgcn_fdot2(wv[c*4+1], u2h(hh.y), acc, false);
                acc = __builtin_amdgcn_fdot2(wv[c*4+2], u2h(hh.z), acc, false);
                acc = __builtin_amdgcn_fdot2(wv[c*4+3], u2h(hh.w), acc, false);
            }
        }
        __syncthreads();   // B: remote h2 ready

        // --- C: remote-half dots
        {
            const unsigned int* hrem = &h2lds[par][(1-p)*128];
            #pragma unroll
            for (int c = 0; c < 32; ++c) {
                uint4 hh = *(const uint4*)(hrem + c*4);
                acc = __builtin_amdgcn_fdot2(wv[128+c*4+0], u2h(hh.x), acc, false);
                acc = __builtin_amdgcn_fdot2(wv[128+c*4+1], u2h(hh.y), acc, false);
                acc = __builtin_amdgcn_fdot2(wv[128+c*4+2], u2h(hh.z), acc, false);
                acc = __builtin_amdgcn_fdot2(wv[128+c*4+3], u2h(hh.w), acc, false);
            }
        }

        // --- D: gates via shfl gather; nonlinearity; stage h_{t+1}
        float sum = acc + gx_cur;
        float gi = __shfl(sum, iout);
        float gf = __shfl(sum, 16 + iout);
        float gg = __shfl(sum, 32 + iout);
        float go = __shfl(sum, 48 + iout);
        float c  = sigf(gf)*creg + sigf(gi)*tanhfast(gg);
        creg = c;
        float hn = sigf(go)*tanhfast(c);          // true h
        float hnb = __shfl(hn, lane | 1);         // even lanes: partner's h
        if (q == 0) {
            hpub[w*16 + iout] = hn + 2.0f;
            if ((iout & 1) == 0)
                h2lds[parn][p*128 + w*8 + (iout >> 1)] = packh2(hn, hnb);
        }
        __syncthreads();   // E: hpub + h2(next) complete

        // --- F: single-instruction 1KB publish of own half of row t+1
        if (w == 14) {
            v4f hv = *(const v4f*)&hpub[lane*4];
            float* dst = hext + (size_t)(t+1)*HD + own0 + lane*4;
            asm volatile("global_store_dwordx4 %0, %1, off sc0 sc1"
                         :: "v"(dst), "v"(hv) : "memory");
        }
        gx_cur = gx_nxt;
    }
}

// ---------------------------------------------------------------------------
// K4: tag projection + log_softmax. Reads hext rows 1..S_LEN (+2 bias).
// ---------------------------------------------------------------------------
__global__ __launch_bounds__(256) void k_out(
    const float* __restrict__ outs_b, const float* __restrict__ W_out,
    const float* __restrict__ b_out, float* __restrict__ out)
{
    __shared__ float hh[16][HD + 4];
    __shared__ float ts[16][TAGS + 4];
    __shared__ float lse[16];
    const int tid = threadIdx.x;
    const int w0  = blockIdx.x * 16;

    {
        int w = tid >> 4, k0 = (tid & 15) * 32;
        #pragma unroll
        for (int i4 = 0; i4 < 8; ++i4) {
            float4 v = *(const float4*)(outs_b + (size_t)(w0+w)*HD + k0 + i4*4);
            int k = k0 + i4*4;
            hh[w][k+0] = v.x - 2.0f; hh[w][k+1] = v.y - 2.0f;
            hh[w][k+2] = v.z - 2.0f; hh[w][k+3] = v.w - 2.0f;
        }
    }
    __syncthreads();

    const int tag = tid & 63;
    const int wg  = tid >> 6;
    float a0 = 0.f, a1 = 0.f, a2 = 0.f, a3 = 0.f;
    for (int kc = 0; kc < HD/4; ++kc) {
        int k = kc * 4;
        float4 wv = *(const float4*)(W_out + (size_t)tag*HD + k);
        float4 x0 = *(const float4*)&hh[wg*4+0][k];
        float4 x1 = *(const float4*)&hh[wg*4+1][k];
        float4 x2 = *(const float4*)&hh[wg*4+2][k];
        float4 x3 = *(const float4*)&hh[wg*4+3][k];
        a0 += wv.x*x0.x + wv.y*x0.y + wv.z*x0.z + wv.w*x0.w;
        a1 += wv.x*x1.x + wv.y*x1.y + wv.z*x1.z + wv.w*x1.w;
        a2 += wv.x*x2.x + wv.y*x2.y + wv.z*x2.z + wv.w*x2.w;
        a3 += wv.x*x3.x + wv.y*x3.y + wv.z*x3.z + wv.w*x3.w;
    }
    float bo = b_out[tag];
    ts[wg*4+0][tag] = a0 + bo;
    ts[wg*4+1][tag] = a1 + bo;
    ts[wg*4+2][tag] = a2 + bo;
    ts[wg*4+3][tag] = a3 + bo;
    __syncthreads();

    if (tid < 16) {
        float m = -1e30f;
        for (int q = 0; q < TAGS; ++q) m = fmaxf(m, ts[tid][q]);
        float ssum = 0.0f;
        for (int q = 0; q < TAGS; ++q) ssum += __expf(ts[tid][q] - m);
        lse[tid] = m + __logf(ssum);
    }
    __syncthreads();

    #pragma unroll
    for (int jjj = 0; jjj < 4; ++jjj)
        out[(size_t)(w0 + wg*4 + jjj)*TAGS + tag] = ts[wg*4+jjj][tag] - lse[wg*4+jjj];
}

// ---------------------------------------------------------------------------
extern "C" void kernel_launch(void* const* d_in, const int* in_sizes, int n_in,
                              void* d_out, int out_size, void* d_ws, size_t ws_size,
                              hipStream_t stream) {
    (void)in_sizes; (void)n_in; (void)out_size; (void)ws_size;
    const int*   w_seq    = (const int*)  d_in[0];
    const int*   c_seq    = (const int*)  d_in[1];
    const float* char_emb = (const float*)d_in[2];
    const float* word_emb = (const float*)d_in[3];
    const float* c_hx0    = (const float*)d_in[4];
    const float* c_cx0    = (const float*)d_in[5];
    const float* hx0      = (const float*)d_in[6];
    const float* cx0      = (const float*)d_in[7];
    const float* Wih1     = (const float*)d_in[8];
    const float* Whh1     = (const float*)d_in[9];
    const float* bih1     = (const float*)d_in[10];
    const float* bhh1     = (const float*)d_in[11];
    const float* Wih2     = (const float*)d_in[12];
    const float* Whh2     = (const float*)d_in[13];
    const float* bih2     = (const float*)d_in[14];
    const float* bhh2     = (const float*)d_in[15];
    const float* W_out    = (const float*)d_in[16];
    const float* b_out    = (const float*)d_in[17];

    float* ws   = (float*)d_ws;
    float* Gx   = ws + WS_GX;
    float* crep = ws + WS_CREP;
    float* hext = ws + WS_HEXT;

    int init_blocks = (int)(((size_t)(S_LEN + 1) * HD / 4 + 255) / 256);
    hipLaunchKernelGGL(k_init, dim3(init_blocks), dim3(256), 0, stream, hx0, hext);
    hipLaunchKernelGGL(k_char_lstm, dim3(256), dim3(256), 0, stream,
                       c_seq, char_emb, c_hx0, c_cx0, Wih1, Whh1, bih1, bhh1, crep);
    hipLaunchKernelGGL(k_gx, dim3(256, 4), dim3(256), 0, stream,
                       w_seq, word_emb, crep, Wih2, bih2, bhh2, Gx);
    hipLaunchKernelGGL(k_word_lstm, dim3(2), dim3(1024), 0, stream,
                       Gx, Whh2, cx0, hext);
    hipLaunchKernelGGL(k_out, dim3(256), dim3(256), 0, stream,
                       hext + HD, W_out, b_out, (float*)d_out);
}